// Round 2
// baseline (152.842 us; speedup 1.0000x reference)
//
#include <hip/hip_runtime.h>

#define EPSF 1e-8f
#define DD 128   // feature dim, fixed by problem

// ---------- small helpers ----------
__device__ __forceinline__ float4 ld4(const float* p){ return *reinterpret_cast<const float4*>(p); }
__device__ __forceinline__ void st4(float* p, const float4& v){ *reinterpret_cast<float4*>(p) = v; }
__device__ __forceinline__ float dot4(const float4& a, const float4& b){
  return a.x*b.x + a.y*b.y + a.z*b.z + a.w*b.w;
}
__device__ __forceinline__ void fma4(float4& acc, const float4& a, float s){
  acc.x += a.x*s; acc.y += a.y*s; acc.z += a.z*s; acc.w += a.w*s;
}
// (1-a)*v + a*x  (matches reference arithmetic order)
__device__ __forceinline__ float4 mix4(float a, const float4& v, const float4& x){
  float4 r;
  r.x = (1.f-a)*v.x + a*x.x;
  r.y = (1.f-a)*v.y + a*x.y;
  r.z = (1.f-a)*v.z + a*x.z;
  r.w = (1.f-a)*v.w + a*x.w;
  return r;
}
// butterfly sum over a 32-lane group (masks <32 stay within each wave half)
__device__ __forceinline__ float red32(float v){
  v += __shfl_xor(v, 1);
  v += __shfl_xor(v, 2);
  v += __shfl_xor(v, 4);
  v += __shfl_xor(v, 8);
  v += __shfl_xor(v, 16);
  return v;
}
// block-level reduction of 8 row-groups' float4 partials into dst[0..127]
__device__ __forceinline__ void block_red(float* red, int group, int l, int t,
                                          const float4& acc, float* dst){
  red[group*DD + l*4+0] = acc.x;
  red[group*DD + l*4+1] = acc.y;
  red[group*DD + l*4+2] = acc.z;
  red[group*DD + l*4+3] = acc.w;
  __syncthreads();
  if (t < DD){
    float s = 0.f;
    #pragma unroll
    for (int g = 0; g < 8; ++g) s += red[g*DD + t];
    dst[t] = s;
  }
  __syncthreads();
}

// ---------- kernel A: cs0 = cos(at_addr, addresses); row-norm field; partials for fn,arg ----------
__global__ __launch_bounds__(256) void kA(const float* __restrict__ at,
                                          const float* __restrict__ addr,
                                          const float* __restrict__ col1,
                                          const float* __restrict__ col2,
                                          float* __restrict__ cs0,
                                          float* __restrict__ naf,
                                          float* __restrict__ part,
                                          int B, int N, int chunks){
  __shared__ float red[8*DD];
  int blk = blockIdx.x;
  int b = blk / chunks, c = blk % chunks;
  int rows = N / chunks, n0 = c * rows;
  int t = threadIdx.x, lane = t & 63, wave = t >> 6, l = lane & 31;
  int group = wave*2 + (lane >> 5);           // 0..7, each group = 32 lanes = 1 row

  float4 at4 = ld4(at + (size_t)b*DD + l*4);
  float nat = sqrtf(red32(dot4(at4, at4)));

  float4 accF = make_float4(0,0,0,0), accA = make_float4(0,0,0,0);
  for (int r = group; r < rows; r += 8){
    size_t n = (size_t)n0 + r;
    size_t off = ((size_t)b*N + n)*DD + l*4;
    float4 a4 = ld4(addr + off);
    float4 c1 = ld4(col1 + off), c2 = ld4(col2 + off);
    float dp = red32(dot4(at4, a4));
    float n2 = red32(dot4(a4, a4));
    float na = sqrtf(n2);
    float cs = dp / fmaxf(nat * na, EPSF);
    if (l == 0){ cs0[(size_t)b*N + n] = cs; naf[(size_t)b*N + n] = na; }
    fma4(accF, c1, cs);
    fma4(accA, c2, cs);
  }
  block_red(red, group, l, t, accF, part + (((size_t)(0*B + b))*chunks + c)*DD);
  block_red(red, group, l, t, accA, part + (((size_t)(1*B + b))*chunks + c)*DD);
}

// ---------- finalize: dst[vec][b][d] = sum_c part[vec][b][c][d] ----------
__global__ void kFin(const float* __restrict__ part, float* __restrict__ dst,
                     int nvec, int B, int chunks){
  int i = blockIdx.x*blockDim.x + threadIdx.x;
  int total = nvec * B * DD;
  if (i >= total) return;
  int d = i & (DD-1);
  int vb = i >> 7;                 // vec*B + b
  const float* p = part + ((size_t)vb*chunks)*DD + d;
  float s = 0.f;
  for (int c = 0; c < chunks; ++c) s += p[(size_t)c*DD];
  dst[i] = s;
}

// ---------- kernel B: cs_fn field; partials for param,body,a_tag,a_l,a_r ----------
__global__ __launch_bounds__(256) void kB(const float* __restrict__ addr,
                                          const float* __restrict__ tags,
                                          const float* __restrict__ col1,
                                          const float* __restrict__ col2,
                                          const float* __restrict__ vecs,
                                          const float* __restrict__ naf,
                                          float* __restrict__ csfn,
                                          float* __restrict__ part,
                                          int B, int N, int chunks){
  __shared__ float red[8*DD];
  int blk = blockIdx.x;
  int b = blk / chunks, c = blk % chunks;
  int rows = N / chunks, n0 = c * rows;
  int t = threadIdx.x, lane = t & 63, wave = t >> 6, l = lane & 31;
  int group = wave*2 + (lane >> 5);

  float4 fn4 = ld4(vecs + ((size_t)0*B + b)*DD + l*4);
  float4 ag4 = ld4(vecs + ((size_t)1*B + b)*DD + l*4);
  float nfn = sqrtf(red32(dot4(fn4, fn4)));
  float nag = sqrtf(red32(dot4(ag4, ag4)));

  float4 accP = make_float4(0,0,0,0), accB = accP, accT = accP, accL = accP, accR = accP;
  for (int r = group; r < rows; r += 8){
    size_t n = (size_t)n0 + r;
    size_t off = ((size_t)b*N + n)*DD + l*4;
    float4 a4 = ld4(addr + off);
    float4 t4 = ld4(tags + off), c1 = ld4(col1 + off), c2 = ld4(col2 + off);
    float na = naf[(size_t)b*N + n];
    float dfn = red32(dot4(fn4, a4));
    float dag = red32(dot4(ag4, a4));
    float cf = dfn / fmaxf(nfn*na, EPSF);
    float ca = dag / fmaxf(nag*na, EPSF);
    if (l == 0) csfn[(size_t)b*N + n] = cf;
    fma4(accP, c1, cf);      // param_addr
    fma4(accB, c2, cf);      // body_addr
    fma4(accT, t4, ca);      // a_tag
    fma4(accL, c1, ca);      // a_l
    fma4(accR, c2, ca);      // a_r
  }
  block_red(red, group, l, t, accP, part + (((size_t)(0*B + b))*chunks + c)*DD);
  block_red(red, group, l, t, accB, part + (((size_t)(1*B + b))*chunks + c)*DD);
  block_red(red, group, l, t, accT, part + (((size_t)(2*B + b))*chunks + c)*DD);
  block_red(red, group, l, t, accL, part + (((size_t)(3*B + b))*chunks + c)*DD);
  block_red(red, group, l, t, accR, part + (((size_t)(4*B + b))*chunks + c)*DD);
}

// ---------- kernel C (reduce-only): row-local scalars + b_tag/b_l/b_r partials ----------
__global__ __launch_bounds__(256) void kC(const float* __restrict__ addr,
                                          const float* __restrict__ tags,
                                          const float* __restrict__ col1,
                                          const float* __restrict__ col2,
                                          const float* __restrict__ vecs,
                                          const float* __restrict__ naf,
                                          float* __restrict__ alphap,
                                          float* __restrict__ csbody,
                                          float* __restrict__ s1f,
                                          float* __restrict__ s2f,
                                          float* __restrict__ part,
                                          int B, int N, int chunks){
  __shared__ float red[8*DD];
  int blk = blockIdx.x;
  int b = blk / chunks, c = blk % chunks;
  int rows = N / chunks, n0 = c * rows;
  int t = threadIdx.x, lane = t & 63, wave = t >> 6, l = lane & 31;
  int group = wave*2 + (lane >> 5);

  size_t BD = (size_t)B*DD;
  float4 ag4 = ld4(vecs + 1*BD + (size_t)b*DD + l*4);   // arg_addr
  float4 pm4 = ld4(vecs + 2*BD + (size_t)b*DD + l*4);   // param_addr
  float4 bd4 = ld4(vecs + 3*BD + (size_t)b*DD + l*4);   // body_addr
  float4 xt4 = ld4(vecs + 4*BD + (size_t)b*DD + l*4);   // a_tag
  float4 xl4 = ld4(vecs + 5*BD + (size_t)b*DD + l*4);   // a_l
  float4 xr4 = ld4(vecs + 6*BD + (size_t)b*DD + l*4);   // a_r
  float npm = sqrtf(red32(dot4(pm4, pm4)));
  float nbd = sqrtf(red32(dot4(bd4, bd4)));

  float4 accT = make_float4(0,0,0,0), accL = accT, accR = accT;
  for (int r = group; r < rows; r += 8){
    size_t n = (size_t)n0 + r;
    size_t off = ((size_t)b*N + n)*DD + l*4;
    float4 a4 = ld4(addr + off);
    float4 t4 = ld4(tags + off), c1 = ld4(col1 + off), c2 = ld4(col2 + off);
    float na = naf[(size_t)b*N + n];
    float dp  = red32(dot4(pm4, a4));
    float db  = red32(dot4(bd4, a4));
    float csp = dp / fmaxf(npm*na, EPSF);
    float ap  = csp > EPSF ? csp : 0.f;
    float csb = db / fmaxf(nbd*na, EPSF);

    // kv_insert with param_addr
    float4 tn  = mix4(ap, t4, xt4);
    float4 c1n = mix4(ap, c1, xl4);
    float4 c2n = mix4(ap, c2, xr4);
    // replace(arg_addr, param_addr, ·): sim vs updated row itself (no clamp)
    float d1  = red32(dot4(pm4, c1n));
    float n21 = red32(dot4(c1n, c1n));
    float s1 = d1 / fmaxf(npm * sqrtf(n21), EPSF);
    float4 c1f = mix4(s1, c1n, ag4);
    float d2  = red32(dot4(pm4, c2n));
    float n22 = red32(dot4(c2n, c2n));
    float s2 = d2 / fmaxf(npm * sqrtf(n22), EPSF);
    float4 c2f = mix4(s2, c2n, ag4);

    if (l == 0){
      alphap[(size_t)b*N + n] = ap;
      csbody[(size_t)b*N + n] = csb;
      s1f[(size_t)b*N + n] = s1;
      s2f[(size_t)b*N + n] = s2;
    }
    // select_address(body_addr, ...) over UPDATED tensors
    fma4(accT, tn,  csb);
    fma4(accL, c1f, csb);
    fma4(accR, c2f, csb);
  }
  block_red(red, group, l, t, accT, part + (((size_t)(0*B + b))*chunks + c)*DD);
  block_red(red, group, l, t, accL, part + (((size_t)(1*B + b))*chunks + c)*DD);
  block_red(red, group, l, t, accR, part + (((size_t)(2*B + b))*chunks + c)*DD);
}

// ---------- kernel E: pure streaming final pass — recompute row updates from fields,
//            apply at-insert + collapsed GC, single write of all 3 outputs ----------
__global__ __launch_bounds__(256) void kE(const float* __restrict__ tags,
                                          const float* __restrict__ col1,
                                          const float* __restrict__ col2,
                                          float* __restrict__ o_t,
                                          float* __restrict__ o_1,
                                          float* __restrict__ o_2,
                                          const float* __restrict__ cs0,
                                          const float* __restrict__ csfn,
                                          const float* __restrict__ alphap,
                                          const float* __restrict__ csbody,
                                          const float* __restrict__ s1f,
                                          const float* __restrict__ s2f,
                                          const float* __restrict__ vecs,
                                          const float* __restrict__ zv,
                                          const int* __restrict__ gcp,
                                          int B, int N){
  size_t i = (size_t)blockIdx.x*blockDim.x + threadIdx.x;
  size_t total = (size_t)B*N*(DD/4);
  if (i >= total) return;
  int l = (int)(i & 31);
  size_t bn = i >> 5;
  int b = (int)(bn / (size_t)N);

  float ap = alphap[bn], s1 = s1f[bn], s2 = s2f[bn];
  float c0 = cs0[bn], cf = csfn[bn], cb = csbody[bn];
  float aat = c0 > EPSF ? c0 : 0.f;
  float af  = cf > EPSF ? cf : 0.f;
  float ab  = cb > EPSF ? cb : 0.f;
  float q = (1.f-af)*(1.f-ap)*(1.f-ab);
  int gc = gcp[0];
  float P = 1.f;
  for (int k = 0; k < gc; ++k) P *= q;

  size_t BD = (size_t)B*DD;
  const float* vb = vecs + (size_t)b*DD + (size_t)l*4;
  float4 ag = ld4(vb + 1*BD);
  float4 xt = ld4(vb + 4*BD), xl = ld4(vb + 5*BD), xr = ld4(vb + 6*BD);
  float4 bt = ld4(vb + 7*BD), bl = ld4(vb + 8*BD), br = ld4(vb + 9*BD);
  float4 z4 = ld4(zv + l*4);

  size_t off = bn*DD + (size_t)l*4;
  float4 t4 = ld4(tags + off), c1 = ld4(col1 + off), c2 = ld4(col2 + off);

  float4 tn  = mix4(ap, t4, xt);                 // param insert
  float4 c1f = mix4(s1, mix4(ap, c1, xl), ag);   // + replace
  float4 c2f = mix4(s2, mix4(ap, c2, xr), ag);

  float4 u;
  u = mix4(aat, tn, bt);                         // body insert at App node
  u.x = P*u.x + (1.f-P)*z4.x; u.y = P*u.y + (1.f-P)*z4.y;
  u.z = P*u.z + (1.f-P)*z4.z; u.w = P*u.w + (1.f-P)*z4.w;
  st4(o_t + off, u);
  u = mix4(aat, c1f, bl);
  u.x = P*u.x + (1.f-P)*z4.x; u.y = P*u.y + (1.f-P)*z4.y;
  u.z = P*u.z + (1.f-P)*z4.z; u.w = P*u.w + (1.f-P)*z4.w;
  st4(o_1 + off, u);
  u = mix4(aat, c2f, br);
  u.x = P*u.x + (1.f-P)*z4.x; u.y = P*u.y + (1.f-P)*z4.y;
  u.z = P*u.z + (1.f-P)*z4.z; u.w = P*u.w + (1.f-P)*z4.w;
  st4(o_2 + off, u);
}

extern "C" void kernel_launch(void* const* d_in, const int* in_sizes, int n_in,
                              void* d_out, int out_size, void* d_ws, size_t ws_size,
                              hipStream_t stream){
  const float* at   = (const float*)d_in[0];
  const float* addr = (const float*)d_in[1];
  const float* tags = (const float*)d_in[2];
  const float* col1 = (const float*)d_in[3];
  const float* col2 = (const float*)d_in[4];
  const float* zv   = (const float*)d_in[5];
  const int*   gc   = (const int*)d_in[6];

  int Dd = in_sizes[5];                 // 128
  int B  = in_sizes[0] / Dd;            // 32
  int N  = in_sizes[1] / in_sizes[0];   // 2048
  (void)Dd;

  size_t S  = (size_t)B * N;
  size_t BD = (size_t)B * DD;

  // chunks per batch: target 2048 blocks (8/CU = 32 waves/CU), shrink if ws too small
  int CH = 64;
  while (CH > 1){
    size_t need = (7*S + 10*BD + (size_t)5*B*CH*DD) * sizeof(float);
    if (need <= ws_size && (N % CH) == 0) break;
    CH >>= 1;
  }

  // workspace layout (floats)
  float* w = (float*)d_ws;
  float* cs0    = w;
  float* csfn   = w + S;
  float* alphap = w + 2*S;
  float* csbody = w + 3*S;
  float* s1f    = w + 4*S;
  float* s2f    = w + 5*S;
  float* naf    = w + 6*S;
  float* vecs   = w + 7*S;              // [10][B][D]: fn,arg,param,body,a_tag,a_l,a_r,b_tag,b_l,b_r
  float* part   = vecs + 10*BD;         // up to [5][B][CH][D]

  float* o_t = (float*)d_out;
  float* o_1 = o_t + (size_t)B*N*DD;
  float* o_2 = o_1 + (size_t)B*N*DD;

  dim3 blk(256);
  dim3 grid(B*CH);

  kA<<<grid, blk, 0, stream>>>(at, addr, col1, col2, cs0, naf, part, B, N, CH);
  {
    int tot = 2*B*DD;
    kFin<<<(tot+255)/256, 256, 0, stream>>>(part, vecs + 0*BD, 2, B, CH);
  }
  kB<<<grid, blk, 0, stream>>>(addr, tags, col1, col2, vecs, naf, csfn, part, B, N, CH);
  {
    int tot = 5*B*DD;
    kFin<<<(tot+255)/256, 256, 0, stream>>>(part, vecs + 2*BD, 5, B, CH);
  }
  kC<<<grid, blk, 0, stream>>>(addr, tags, col1, col2, vecs, naf, alphap, csbody,
                               s1f, s2f, part, B, N, CH);
  {
    int tot = 3*B*DD;
    kFin<<<(tot+255)/256, 256, 0, stream>>>(part, vecs + 7*BD, 3, B, CH);
  }
  {
    size_t tot = (size_t)B*N*(DD/4);
    kE<<<(unsigned)((tot+255)/256), 256, 0, stream>>>(tags, col1, col2, o_t, o_1, o_2,
                                                      cs0, csfn, alphap, csbody,
                                                      s1f, s2f, vecs, zv, gc, B, N);
  }
}

// Round 3
// 126.253 us; speedup vs baseline: 1.2106x; 1.2106x over previous
//
#include <hip/hip_runtime.h>

#define EPSF 1e-8f
#define DD 128   // feature dim, fixed by problem

// ---------- small helpers ----------
__device__ __forceinline__ float4 ld4(const float* p){ return *reinterpret_cast<const float4*>(p); }
__device__ __forceinline__ void st4(float* p, const float4& v){ *reinterpret_cast<float4*>(p) = v; }
__device__ __forceinline__ float dot4(const float4& a, const float4& b){
  return a.x*b.x + a.y*b.y + a.z*b.z + a.w*b.w;
}
__device__ __forceinline__ void fma4(float4& acc, const float4& a, float s){
  acc.x += a.x*s; acc.y += a.y*s; acc.z += a.z*s; acc.w += a.w*s;
}
// (1-a)*v + a*x  (matches reference arithmetic order)
__device__ __forceinline__ float4 mix4(float a, const float4& v, const float4& x){
  float4 r;
  r.x = (1.f-a)*v.x + a*x.x;
  r.y = (1.f-a)*v.y + a*x.y;
  r.z = (1.f-a)*v.z + a*x.z;
  r.w = (1.f-a)*v.w + a*x.w;
  return r;
}
// butterfly sum over a 16-lane group (xor masks stay within the group)
__device__ __forceinline__ float red16(float v){
  v += __shfl_xor(v, 1);
  v += __shfl_xor(v, 2);
  v += __shfl_xor(v, 4);
  v += __shfl_xor(v, 8);
  return v;
}
// block-level reduction of 16 row-groups' (2x float4 per lane) partials into dst[0..127]
__device__ __forceinline__ void block_red16(float* red, int g, int l, int t,
                                            const float4& accA, const float4& accB,
                                            float* dst){
  red[g*DD + l*4+0] = accA.x;
  red[g*DD + l*4+1] = accA.y;
  red[g*DD + l*4+2] = accA.z;
  red[g*DD + l*4+3] = accA.w;
  red[g*DD + 64 + l*4+0] = accB.x;
  red[g*DD + 64 + l*4+1] = accB.y;
  red[g*DD + 64 + l*4+2] = accB.z;
  red[g*DD + 64 + l*4+3] = accB.w;
  __syncthreads();
  if (t < DD){
    float s = 0.f;
    #pragma unroll
    for (int q = 0; q < 16; ++q) s += red[q*DD + t];
    dst[t] = s;
  }
  __syncthreads();
}

// ---------- kernel A: cs0 = cos(at_addr, addresses); row-norm field; partials for fn,arg ----------
__global__ __launch_bounds__(256) void kA(const float* __restrict__ at,
                                          const float* __restrict__ addr,
                                          const float* __restrict__ col1,
                                          const float* __restrict__ col2,
                                          float* __restrict__ cs0,
                                          float* __restrict__ naf,
                                          float* __restrict__ part,
                                          int B, int N, int chunks){
  __shared__ float red[16*DD];
  int blk = blockIdx.x;
  int b = blk / chunks, c = blk % chunks;
  int rows = N / chunks, n0 = c * rows;
  int t = threadIdx.x, g = t >> 4, l = t & 15;   // 16 groups of 16 lanes; group = 1 row
  size_t bN = (size_t)b * N;

  const float* atp = at + (size_t)b*DD;
  float4 atA = ld4(atp + l*4), atB = ld4(atp + 64 + l*4);
  float nat = sqrtf(red16(dot4(atA, atA) + dot4(atB, atB)));

  float4 accFA = make_float4(0,0,0,0), accFB = accFA, accAA = accFA, accAB = accFA;
  #pragma unroll 2
  for (int r = g; r < rows; r += 16){
    size_t n = (size_t)n0 + r;
    size_t base = (bN + n)*DD;
    float4 aA  = ld4(addr + base + l*4), aB  = ld4(addr + base + 64 + l*4);
    float4 c1A = ld4(col1 + base + l*4), c1B = ld4(col1 + base + 64 + l*4);
    float4 c2A = ld4(col2 + base + l*4), c2B = ld4(col2 + base + 64 + l*4);
    float dp = red16(dot4(atA, aA) + dot4(atB, aB));
    float n2 = red16(dot4(aA, aA) + dot4(aB, aB));
    float na = sqrtf(n2);
    float cs = dp / fmaxf(nat * na, EPSF);
    if (l == 0){ cs0[bN + n] = cs; naf[bN + n] = na; }
    fma4(accFA, c1A, cs); fma4(accFB, c1B, cs);
    fma4(accAA, c2A, cs); fma4(accAB, c2B, cs);
  }
  block_red16(red, g, l, t, accFA, accFB, part + (((size_t)(0*B + b))*chunks + c)*DD);
  block_red16(red, g, l, t, accAA, accAB, part + (((size_t)(1*B + b))*chunks + c)*DD);
}

// ---------- finalize: dst[vec][b][d] = sum_c part[vec][b][c][d] ----------
__global__ void kFin(const float* __restrict__ part, float* __restrict__ dst,
                     int nvec, int B, int chunks){
  int i = blockIdx.x*blockDim.x + threadIdx.x;
  int total = nvec * B * DD;
  if (i >= total) return;
  int d = i & (DD-1);
  int vb = i >> 7;                 // vec*B + b
  const float* p = part + ((size_t)vb*chunks)*DD + d;
  float s = 0.f;
  for (int c = 0; c < chunks; ++c) s += p[(size_t)c*DD];
  dst[i] = s;
}

// ---------- kernel B: cs_fn field; partials for param,body,a_tag,a_l,a_r ----------
__global__ __launch_bounds__(256) void kB(const float* __restrict__ addr,
                                          const float* __restrict__ tags,
                                          const float* __restrict__ col1,
                                          const float* __restrict__ col2,
                                          const float* __restrict__ vecs,
                                          const float* __restrict__ naf,
                                          float* __restrict__ csfn,
                                          float* __restrict__ part,
                                          int B, int N, int chunks){
  __shared__ float red[16*DD];
  int blk = blockIdx.x;
  int b = blk / chunks, c = blk % chunks;
  int rows = N / chunks, n0 = c * rows;
  int t = threadIdx.x, g = t >> 4, l = t & 15;
  size_t bN = (size_t)b * N;

  const float* fnp = vecs + ((size_t)0*B + b)*DD;
  const float* agp = vecs + ((size_t)1*B + b)*DD;
  float4 fnA = ld4(fnp + l*4), fnB = ld4(fnp + 64 + l*4);
  float4 agA = ld4(agp + l*4), agB = ld4(agp + 64 + l*4);
  float nfn = sqrtf(red16(dot4(fnA, fnA) + dot4(fnB, fnB)));
  float nag = sqrtf(red16(dot4(agA, agA) + dot4(agB, agB)));

  float4 z = make_float4(0,0,0,0);
  float4 accPA=z, accPB=z, accBA=z, accBB=z, accTA=z, accTB=z, accLA=z, accLB=z, accRA=z, accRB=z;
  #pragma unroll 2
  for (int r = g; r < rows; r += 16){
    size_t n = (size_t)n0 + r;
    size_t base = (bN + n)*DD;
    float4 aA  = ld4(addr + base + l*4), aB  = ld4(addr + base + 64 + l*4);
    float4 t4A = ld4(tags + base + l*4), t4B = ld4(tags + base + 64 + l*4);
    float4 c1A = ld4(col1 + base + l*4), c1B = ld4(col1 + base + 64 + l*4);
    float4 c2A = ld4(col2 + base + l*4), c2B = ld4(col2 + base + 64 + l*4);
    float na = naf[bN + n];
    float dfn = red16(dot4(fnA, aA) + dot4(fnB, aB));
    float dag = red16(dot4(agA, aA) + dot4(agB, aB));
    float cf = dfn / fmaxf(nfn*na, EPSF);
    float ca = dag / fmaxf(nag*na, EPSF);
    if (l == 0) csfn[bN + n] = cf;
    fma4(accPA, c1A, cf); fma4(accPB, c1B, cf);      // param_addr
    fma4(accBA, c2A, cf); fma4(accBB, c2B, cf);      // body_addr
    fma4(accTA, t4A, ca); fma4(accTB, t4B, ca);      // a_tag
    fma4(accLA, c1A, ca); fma4(accLB, c1B, ca);      // a_l
    fma4(accRA, c2A, ca); fma4(accRB, c2B, ca);      // a_r
  }
  block_red16(red, g, l, t, accPA, accPB, part + (((size_t)(0*B + b))*chunks + c)*DD);
  block_red16(red, g, l, t, accBA, accBB, part + (((size_t)(1*B + b))*chunks + c)*DD);
  block_red16(red, g, l, t, accTA, accTB, part + (((size_t)(2*B + b))*chunks + c)*DD);
  block_red16(red, g, l, t, accLA, accLB, part + (((size_t)(3*B + b))*chunks + c)*DD);
  block_red16(red, g, l, t, accRA, accRB, part + (((size_t)(4*B + b))*chunks + c)*DD);
}

// ---------- kernel C (reduce-only): row-local scalars + b_tag/b_l/b_r partials ----------
__global__ __launch_bounds__(256) void kC(const float* __restrict__ addr,
                                          const float* __restrict__ tags,
                                          const float* __restrict__ col1,
                                          const float* __restrict__ col2,
                                          const float* __restrict__ vecs,
                                          const float* __restrict__ naf,
                                          float* __restrict__ alphap,
                                          float* __restrict__ csbody,
                                          float* __restrict__ s1f,
                                          float* __restrict__ s2f,
                                          float* __restrict__ part,
                                          int B, int N, int chunks){
  __shared__ float red[16*DD];
  int blk = blockIdx.x;
  int b = blk / chunks, c = blk % chunks;
  int rows = N / chunks, n0 = c * rows;
  int t = threadIdx.x, g = t >> 4, l = t & 15;
  size_t bN = (size_t)b * N;

  size_t BD = (size_t)B*DD;
  const float* vp = vecs + (size_t)b*DD;
  float4 agA = ld4(vp + 1*BD + l*4), agB = ld4(vp + 1*BD + 64 + l*4);  // arg_addr
  float4 pmA = ld4(vp + 2*BD + l*4), pmB = ld4(vp + 2*BD + 64 + l*4);  // param_addr
  float4 bdA = ld4(vp + 3*BD + l*4), bdB = ld4(vp + 3*BD + 64 + l*4);  // body_addr
  float4 xtA = ld4(vp + 4*BD + l*4), xtB = ld4(vp + 4*BD + 64 + l*4);  // a_tag
  float4 xlA = ld4(vp + 5*BD + l*4), xlB = ld4(vp + 5*BD + 64 + l*4);  // a_l
  float4 xrA = ld4(vp + 6*BD + l*4), xrB = ld4(vp + 6*BD + 64 + l*4);  // a_r
  float npm = sqrtf(red16(dot4(pmA, pmA) + dot4(pmB, pmB)));
  float nbd = sqrtf(red16(dot4(bdA, bdA) + dot4(bdB, bdB)));

  float4 z = make_float4(0,0,0,0);
  float4 accTA=z, accTB=z, accLA=z, accLB=z, accRA=z, accRB=z;
  #pragma unroll 2
  for (int r = g; r < rows; r += 16){
    size_t n = (size_t)n0 + r;
    size_t base = (bN + n)*DD;
    float4 aA  = ld4(addr + base + l*4), aB  = ld4(addr + base + 64 + l*4);
    float4 t4A = ld4(tags + base + l*4), t4B = ld4(tags + base + 64 + l*4);
    float4 c1A = ld4(col1 + base + l*4), c1B = ld4(col1 + base + 64 + l*4);
    float4 c2A = ld4(col2 + base + l*4), c2B = ld4(col2 + base + 64 + l*4);
    float na = naf[bN + n];
    float dp = red16(dot4(pmA, aA) + dot4(pmB, aB));
    float db = red16(dot4(bdA, aA) + dot4(bdB, aB));
    float csp = dp / fmaxf(npm*na, EPSF);
    float ap  = csp > EPSF ? csp : 0.f;
    float csb = db / fmaxf(nbd*na, EPSF);

    // kv_insert with param_addr
    float4 tnA  = mix4(ap, t4A, xtA), tnB  = mix4(ap, t4B, xtB);
    float4 c1nA = mix4(ap, c1A, xlA), c1nB = mix4(ap, c1B, xlB);
    float4 c2nA = mix4(ap, c2A, xrA), c2nB = mix4(ap, c2B, xrB);
    // replace(arg_addr, param_addr, ·): sim vs updated row itself (no clamp)
    float d1  = red16(dot4(pmA, c1nA) + dot4(pmB, c1nB));
    float n21 = red16(dot4(c1nA, c1nA) + dot4(c1nB, c1nB));
    float s1 = d1 / fmaxf(npm * sqrtf(n21), EPSF);
    float4 c1fA = mix4(s1, c1nA, agA), c1fB = mix4(s1, c1nB, agB);
    float d2  = red16(dot4(pmA, c2nA) + dot4(pmB, c2nB));
    float n22 = red16(dot4(c2nA, c2nA) + dot4(c2nB, c2nB));
    float s2 = d2 / fmaxf(npm * sqrtf(n22), EPSF);
    float4 c2fA = mix4(s2, c2nA, agA), c2fB = mix4(s2, c2nB, agB);

    if (l == 0){
      alphap[bN + n] = ap;
      csbody[bN + n] = csb;
      s1f[bN + n] = s1;
      s2f[bN + n] = s2;
    }
    // select_address(body_addr, ...) over UPDATED tensors
    fma4(accTA, tnA,  csb); fma4(accTB, tnB,  csb);
    fma4(accLA, c1fA, csb); fma4(accLB, c1fB, csb);
    fma4(accRA, c2fA, csb); fma4(accRB, c2fB, csb);
  }
  block_red16(red, g, l, t, accTA, accTB, part + (((size_t)(0*B + b))*chunks + c)*DD);
  block_red16(red, g, l, t, accLA, accLB, part + (((size_t)(1*B + b))*chunks + c)*DD);
  block_red16(red, g, l, t, accRA, accRB, part + (((size_t)(2*B + b))*chunks + c)*DD);
}

// ---------- kernel E: pure streaming final pass — recompute row updates from fields,
//            apply at-insert + collapsed GC, single write of all 3 outputs ----------
__global__ __launch_bounds__(256) void kE(const float* __restrict__ tags,
                                          const float* __restrict__ col1,
                                          const float* __restrict__ col2,
                                          float* __restrict__ o_t,
                                          float* __restrict__ o_1,
                                          float* __restrict__ o_2,
                                          const float* __restrict__ cs0,
                                          const float* __restrict__ csfn,
                                          const float* __restrict__ alphap,
                                          const float* __restrict__ csbody,
                                          const float* __restrict__ s1f,
                                          const float* __restrict__ s2f,
                                          const float* __restrict__ vecs,
                                          const float* __restrict__ zv,
                                          const int* __restrict__ gcp,
                                          int B, int N){
  size_t i = (size_t)blockIdx.x*blockDim.x + threadIdx.x;
  size_t total = (size_t)B*N*(DD/4);
  if (i >= total) return;
  int l = (int)(i & 31);
  size_t bn = i >> 5;
  int b = (int)(bn / (size_t)N);

  float ap = alphap[bn], s1 = s1f[bn], s2 = s2f[bn];
  float c0 = cs0[bn], cf = csfn[bn], cb = csbody[bn];
  float aat = c0 > EPSF ? c0 : 0.f;
  float af  = cf > EPSF ? cf : 0.f;
  float ab  = cb > EPSF ? cb : 0.f;
  float q = (1.f-af)*(1.f-ap)*(1.f-ab);
  int gc = gcp[0];
  float P = 1.f;
  for (int k = 0; k < gc; ++k) P *= q;

  size_t BD = (size_t)B*DD;
  const float* vb = vecs + (size_t)b*DD + (size_t)l*4;
  float4 ag = ld4(vb + 1*BD);
  float4 xt = ld4(vb + 4*BD), xl = ld4(vb + 5*BD), xr = ld4(vb + 6*BD);
  float4 bt = ld4(vb + 7*BD), bl = ld4(vb + 8*BD), br = ld4(vb + 9*BD);
  float4 z4 = ld4(zv + l*4);

  size_t off = bn*DD + (size_t)l*4;
  float4 t4 = ld4(tags + off), c1 = ld4(col1 + off), c2 = ld4(col2 + off);

  float4 tn  = mix4(ap, t4, xt);                 // param insert
  float4 c1f = mix4(s1, mix4(ap, c1, xl), ag);   // + replace
  float4 c2f = mix4(s2, mix4(ap, c2, xr), ag);

  float4 u;
  u = mix4(aat, tn, bt);                         // body insert at App node
  u.x = P*u.x + (1.f-P)*z4.x; u.y = P*u.y + (1.f-P)*z4.y;
  u.z = P*u.z + (1.f-P)*z4.z; u.w = P*u.w + (1.f-P)*z4.w;
  st4(o_t + off, u);
  u = mix4(aat, c1f, bl);
  u.x = P*u.x + (1.f-P)*z4.x; u.y = P*u.y + (1.f-P)*z4.y;
  u.z = P*u.z + (1.f-P)*z4.z; u.w = P*u.w + (1.f-P)*z4.w;
  st4(o_1 + off, u);
  u = mix4(aat, c2f, br);
  u.x = P*u.x + (1.f-P)*z4.x; u.y = P*u.y + (1.f-P)*z4.y;
  u.z = P*u.z + (1.f-P)*z4.z; u.w = P*u.w + (1.f-P)*z4.w;
  st4(o_2 + off, u);
}

extern "C" void kernel_launch(void* const* d_in, const int* in_sizes, int n_in,
                              void* d_out, int out_size, void* d_ws, size_t ws_size,
                              hipStream_t stream){
  const float* at   = (const float*)d_in[0];
  const float* addr = (const float*)d_in[1];
  const float* tags = (const float*)d_in[2];
  const float* col1 = (const float*)d_in[3];
  const float* col2 = (const float*)d_in[4];
  const float* zv   = (const float*)d_in[5];
  const int*   gc   = (const int*)d_in[6];

  int Dd = in_sizes[5];                 // 128
  int B  = in_sizes[0] / Dd;            // 32
  int N  = in_sizes[1] / in_sizes[0];   // 2048
  (void)Dd;

  size_t S  = (size_t)B * N;
  size_t BD = (size_t)B * DD;

  // chunks per batch: 32 -> grid 1024 blocks (4/CU); shrink if ws too small
  int CH = 32;
  while (CH > 1){
    size_t need = (7*S + 10*BD + (size_t)5*B*CH*DD) * sizeof(float);
    if (need <= ws_size && (N % CH) == 0) break;
    CH >>= 1;
  }

  // workspace layout (floats)
  float* w = (float*)d_ws;
  float* cs0    = w;
  float* csfn   = w + S;
  float* alphap = w + 2*S;
  float* csbody = w + 3*S;
  float* s1f    = w + 4*S;
  float* s2f    = w + 5*S;
  float* naf    = w + 6*S;
  float* vecs   = w + 7*S;              // [10][B][D]: fn,arg,param,body,a_tag,a_l,a_r,b_tag,b_l,b_r
  float* part   = vecs + 10*BD;         // up to [5][B][CH][D]

  float* o_t = (float*)d_out;
  float* o_1 = o_t + (size_t)B*N*DD;
  float* o_2 = o_1 + (size_t)B*N*DD;

  dim3 blk(256);
  dim3 grid(B*CH);

  kA<<<grid, blk, 0, stream>>>(at, addr, col1, col2, cs0, naf, part, B, N, CH);
  {
    int tot = 2*B*DD;
    kFin<<<(tot+255)/256, 256, 0, stream>>>(part, vecs + 0*BD, 2, B, CH);
  }
  kB<<<grid, blk, 0, stream>>>(addr, tags, col1, col2, vecs, naf, csfn, part, B, N, CH);
  {
    int tot = 5*B*DD;
    kFin<<<(tot+255)/256, 256, 0, stream>>>(part, vecs + 2*BD, 5, B, CH);
  }
  kC<<<grid, blk, 0, stream>>>(addr, tags, col1, col2, vecs, naf, alphap, csbody,
                               s1f, s2f, part, B, N, CH);
  {
    int tot = 3*B*DD;
    kFin<<<(tot+255)/256, 256, 0, stream>>>(part, vecs + 7*BD, 3, B, CH);
  }
  {
    size_t tot = (size_t)B*N*(DD/4);
    kE<<<(unsigned)((tot+255)/256), 256, 0, stream>>>(tags, col1, col2, o_t, o_1, o_2,
                                                      cs0, csfn, alphap, csbody,
                                                      s1f, s2f, vecs, zv, gc, B, N);
  }
}